// Round 6
// baseline (40.757 us; speedup 1.0000x reference)
//
#include <hip/hip_runtime.h>

// KA-conv: out[b,o,h,w] = sum_m P_om(v) / (1+|Q_om(v)|), v = zero-padded patch
// value, m = c*9+ki*3+kj, M=144. ~75.5M rational evals, pure fp32 VALU.
//
// R6: R5 (s_load coeffs) was neutral vs R4 (LDS coeffs) -> coefficient pipe
// was NOT the bottleneck; kernel is issue/latency-bound at low occupancy
// (2 waves/SIMD->49% busy, 4->54%). This version maximizes TLP:
//  - 1 output row/thread, 256-thr blocks, grid 2048 -> 8 blocks/CU
//    -> 32 waves/CU = 8 waves/SIMD (hardware max), VGPR must stay <=64.
//  - o = blockIdx&31: the ~8 co-resident blocks per CU share one output
//    channel -> one 5.76KB coefficient set in scalar cache, not eight.
//  - coefficients via wave-uniform s_load (SMEM pipe, off the VALU path).

constexpr int Bn = 4, Cin = 16, Hh = 64, Ww = 64, Oc = 32, Mtot = 144;

__global__ __launch_bounds__(256, 8)
void ka_conv_kernel(const float* __restrict__ x,
                    const float* __restrict__ nums,
                    const float* __restrict__ denoms,
                    float* __restrict__ out) {
  const int tid = threadIdx.x;
  const int n   = blockIdx.x;
  const int o   = n & 31;          // same-CU blocks share o (n mod 256 fixed)
  const int ht  = (n >> 5) & 15;   // 16 height tiles of 4 rows
  const int b   = n >> 9;          // batch

  const int w  = tid & 63;         // output column (lane -> coalesced)
  const int rg = tid >> 6;         // row-in-tile 0..3
  const int h  = ht * 4 + rg;      // this thread's single output row

  // clamped neighbor rows/cols + validity masks (loop-invariant)
  const int  wm  = max(w - 1, 0), wp = min(w + 1, Ww - 1);
  const bool wlv = w > 0, wrv = (w + 1) < Ww;
  const int  hm  = max(h - 1, 0), hp = min(h + 1, Hh - 1);
  const bool htv = h > 0, hbv = (h + 1) < Hh;
  const bool m00 = htv && wlv, m01 = htv, m02 = htv && wrv;
  const bool m10 = wlv,                    m12 = wrv;
  const bool m20 = hbv && wlv, m21 = hbv, m22 = hbv && wrv;

  float acc = 0.f;
  const float* __restrict__ xb   = x + (size_t)b * Cin * Hh * Ww;
  const float* __restrict__ anum = nums   + (size_t)o * Mtot * 6;   // uniform
  const float* __restrict__ bden = denoms + (size_t)o * Mtot * 4;   // uniform

  // one tap: coeff slot t (0..8) of channel c, patch value v -> acc.
  // pa/pb are wave-uniform -> s_load with immediate offsets.
#define TAP(t, v_) do {                                                        \
    const float a0 = pa[(t)*6 + 0], a1 = pa[(t)*6 + 1], a2 = pa[(t)*6 + 2];    \
    const float a3 = pa[(t)*6 + 3], a4 = pa[(t)*6 + 4], a5 = pa[(t)*6 + 5];    \
    const float c1 = pb[(t)*4 + 0], c2 = pb[(t)*4 + 1];                        \
    const float c3 = pb[(t)*4 + 2], c4 = pb[(t)*4 + 3];                        \
    const float v  = (v_);                                                     \
    float num = fmaf(fmaf(fmaf(fmaf(fmaf(a5,v,a4),v,a3),v,a2),v,a1),v,a0);     \
    float dp  = fmaf(fmaf(fmaf(c4,v,c3),v,c2),v,c1) * v;                       \
    float r   = __builtin_amdgcn_rcpf(1.0f + fabsf(dp));                       \
    acc = fmaf(num, r, acc);                                                   \
  } while (0)

  #pragma unroll 2
  for (int c = 0; c < Cin; ++c) {
    const float* __restrict__ xc = xb + (size_t)c * (Hh * Ww);
    const float* __restrict__ r0 = xc + hm * Ww;        // h-1 (clamped)
    const float* __restrict__ r1 = xc + h * Ww;         // h
    const float* __restrict__ r2 = xc + hp * Ww;        // h+1 (clamped)

    // 9 unconditional coalesced loads, then mask halo lanes to zero
    float v00 = r0[wm], v01 = r0[w], v02 = r0[wp];
    float v10 = r1[wm], v11 = r1[w], v12 = r1[wp];
    float v20 = r2[wm], v21 = r2[w], v22 = r2[wp];
    v00 = m00 ? v00 : 0.f;  v01 = m01 ? v01 : 0.f;  v02 = m02 ? v02 : 0.f;
    v10 = m10 ? v10 : 0.f;                          v12 = m12 ? v12 : 0.f;
    v20 = m20 ? v20 : 0.f;  v21 = m21 ? v21 : 0.f;  v22 = m22 ? v22 : 0.f;

    const float* __restrict__ pa = anum + c * 54;   // 9 taps * 6 coeffs
    const float* __restrict__ pb = bden + c * 36;   // 9 taps * 4 coeffs
    TAP(0, v00);  TAP(1, v01);  TAP(2, v02);
    TAP(3, v10);  TAP(4, v11);  TAP(5, v12);
    TAP(6, v20);  TAP(7, v21);  TAP(8, v22);
  }
#undef TAP

  out[((size_t)(b * Oc + o) * Hh + h) * Ww + w] = acc;
}

extern "C" void kernel_launch(void* const* d_in, const int* in_sizes, int n_in,
                              void* d_out, int out_size, void* d_ws, size_t ws_size,
                              hipStream_t stream) {
  const float* x      = (const float*)d_in[0];
  const float* nums   = (const float*)d_in[1];
  const float* denoms = (const float*)d_in[2];
  float* out          = (float*)d_out;
  // blockIdx = b*512 + ht*32 + o  (o in the low bits: same-CU o-sharing)
  dim3 grid(Bn * Oc * 16);
  ka_conv_kernel<<<grid, 256, 0, stream>>>(x, nums, denoms, out);
}